// Round 1
// baseline (325.896 us; speedup 1.0000x reference)
//
#include <hip/hip_runtime.h>
#include <hip/hip_bf16.h>
#include <stdint.h>

#define B_ROWS 16384
#define D_IN   1200
#define D_PAD  1216      // 19 * 64
#define N_EXP  8
#define H_DIM  1024
#define R_CAP  4608      // fixed per-expert region (counts ~4096 +- 55; 9 sigma margin)
#define CAP    36864     // 8 * R_CAP
#define LN_EPS 1e-5f
#define GATE_EPS 1e-6f
#define CNT_STRIDE 16    // pad expert counters to separate 64B cache lines

// ---- workspace layout (bytes) ----
#define O_CNT    0           // 512 B
#define O_PROWC  512         // 36864 ints  -> 147968
#define O_PGATEC 147968      // 36864 floats -> 295424
#define O_XBF    295424      // 16385*1216*2 -> 40143744 (row 16384 = zeros)
#define O_W1T    40143744    // 8*1024*1216*2 -> 60066688
#define O_HBUF   60066688    // 36864*1024*2 -> 135564160 (~130 MB total)

#define GATING_BLOCKS (B_ROWS / 16)       // 1024 (4 rows/wave, 4 waves)
#define W1T_BLOCKS    (19 * 16 * 8)       // 2432  (64d x 64h tiles)

// ---- GEMM geometry: 256x256 tile, BK=32, 8 waves, 4-deep LDS pipeline ----
#define NT        (D_PAD / 32)            // 38 K-tiles
#define LDS_BUF   32768                   // A 16KB + B 16KB per ring slot
#define GEMM_BLOCKS (N_EXP * (R_CAP / 256) * (H_DIM / 256))   // 8*18*4 = 576

typedef short bf16x8 __attribute__((ext_vector_type(8)));
typedef short short8 __attribute__((ext_vector_type(8)));
typedef short short4v __attribute__((ext_vector_type(4)));
typedef float f32x4 __attribute__((ext_vector_type(4)));

__device__ __forceinline__ void load_lds16(const void* gptr, void* ldsptr) {
    __builtin_amdgcn_global_load_lds(
        (__attribute__((address_space(1))) void*)const_cast<void*>(gptr),
        (__attribute__((address_space(3))) void*)ldsptr, 16, 0, 0);
}

__device__ __forceinline__ short4v pack_bf16x4(float4 a) {
    union { short4v v; __hip_bfloat16 h[4]; } u;
    u.h[0] = __float2bfloat16(a.x); u.h[1] = __float2bfloat16(a.y);
    u.h[2] = __float2bfloat16(a.z); u.h[3] = __float2bfloat16(a.w);
    return u.v;
}

// ---------------- 1a. gating (4 rows/wave) + x->bf16 + direct scatter + y zero ----------------
__global__ __launch_bounds__(256) void gating_kernel(
    const float* __restrict__ x, const float* __restrict__ wg,
    int* __restrict__ cnt, int* __restrict__ pairRowC, float* __restrict__ pairGateC,
    __hip_bfloat16* __restrict__ xbf, float* __restrict__ y)
{
    __shared__ int lcnt[N_EXP];
    __shared__ int base[N_EXP];
    int bx = blockIdx.x;
    int tid = threadIdx.x;

    if (bx == GATING_BLOCKS) {   // zero the padding row of xbf
        short8* xrow = (short8*)(xbf + (long)B_ROWS * D_PAD);
        if (tid < 152) xrow[tid] = (short8){0, 0, 0, 0, 0, 0, 0, 0};
        return;
    }

    if (tid < N_EXP) lcnt[tid] = 0;
    if (tid < 16) y[bx * 16 + tid] = 0.f;
    __syncthreads();

    int widx = tid >> 6;
    int lane = tid & 63;
    int rowbase = bx * 16 + widx * 4;
    const float* xw = x + (long)rowbase * D_IN;

    float acc[4][8];
#pragma unroll
    for (int r = 0; r < 4; ++r)
#pragma unroll
        for (int e = 0; e < N_EXP; ++e) acc[r][e] = 0.f;

    for (int i = lane; i < 304; i += 64) {
        if (i < 300) {
            const float4* wv4 = (const float4*)(wg + (long)i * 32);
            float4 w0 = wv4[0], w1v = wv4[1], w2 = wv4[2], w3 = wv4[3],
                   w4 = wv4[4], w5 = wv4[5], w6 = wv4[6], w7 = wv4[7];
#pragma unroll
            for (int r = 0; r < 4; ++r) {
                float4 xv = ((const float4*)(xw + (long)r * D_IN))[i];
                acc[r][0] += xv.x * w0.x + xv.y * w2.x + xv.z * w4.x + xv.w * w6.x;
                acc[r][1] += xv.x * w0.y + xv.y * w2.y + xv.z * w4.y + xv.w * w6.y;
                acc[r][2] += xv.x * w0.z + xv.y * w2.z + xv.z * w4.z + xv.w * w6.z;
                acc[r][3] += xv.x * w0.w + xv.y * w2.w + xv.z * w4.w + xv.w * w6.w;
                acc[r][4] += xv.x * w1v.x + xv.y * w3.x + xv.z * w5.x + xv.w * w7.x;
                acc[r][5] += xv.x * w1v.y + xv.y * w3.y + xv.z * w5.y + xv.w * w7.y;
                acc[r][6] += xv.x * w1v.z + xv.y * w3.z + xv.z * w5.z + xv.w * w7.z;
                acc[r][7] += xv.x * w1v.w + xv.y * w3.w + xv.z * w5.w + xv.w * w7.w;
                ((short4v*)(xbf + (long)(rowbase + r) * D_PAD))[i] = pack_bf16x4(xv);
            }
        } else {
#pragma unroll
            for (int r = 0; r < 4; ++r)
                ((short4v*)(xbf + (long)(rowbase + r) * D_PAD))[i] = (short4v){0, 0, 0, 0};
        }
    }

#pragma unroll
    for (int r = 0; r < 4; ++r)
#pragma unroll
        for (int e = 0; e < N_EXP; ++e) {
            float v = acc[r][e];
#pragma unroll
            for (int off = 32; off > 0; off >>= 1) v += __shfl_xor(v, off, 64);
            acc[r][e] = v;
        }

    float my[N_EXP];
#pragma unroll
    for (int e = 0; e < N_EXP; ++e) my[e] = acc[0][e];
#pragma unroll
    for (int r = 1; r < 4; ++r)
#pragma unroll
        for (int e = 0; e < N_EXP; ++e)
            if (lane == r) my[e] = acc[r][e];

    int i0 = 0, i1 = 1, s0 = 0, s1 = 0;
    float g0 = 0.f, g1 = 0.f;
    if (lane < 4) {
        float m = my[0];
#pragma unroll
        for (int e = 1; e < N_EXP; ++e) m = fmaxf(m, my[e]);
        float p[N_EXP], s = 0.f;
#pragma unroll
        for (int e = 0; e < N_EXP; ++e) { p[e] = expf(my[e] - m); s += p[e]; }
#pragma unroll
        for (int e = 1; e < N_EXP; ++e) if (p[e] > p[i0]) i0 = e;
        i1 = (i0 == 0) ? 1 : 0;
#pragma unroll
        for (int e = 0; e < N_EXP; ++e) if (e != i0 && p[e] > p[i1]) i1 = e;
        float v0 = p[i0] / s, v1 = p[i1] / s;
        float inv = 1.f / (v0 + v1 + GATE_EPS);
        g0 = v0 * inv; g1 = v1 * inv;
        s0 = atomicAdd(&lcnt[i0], 1);
        s1 = atomicAdd(&lcnt[i1], 1);
    }
    __syncthreads();
    if (tid < N_EXP) base[tid] = atomicAdd(&cnt[tid * CNT_STRIDE], lcnt[tid]);
    __syncthreads();
    if (lane < 4) {
        int row = rowbase + lane;
        int p0 = i0 * R_CAP + base[i0] + s0;
        pairRowC[p0] = row; pairGateC[p0] = g0;
        int p1 = i1 * R_CAP + base[i1] + s1;
        pairRowC[p1] = row; pairGateC[p1] = g1;
    }
}

// ---------------- 1b. W1 [E][D][H] fp32 -> w1t [E][H][D_PAD] bf16 ----------------
__global__ __launch_bounds__(256) void w1t_kernel(
    const float* __restrict__ W1, __hip_bfloat16* __restrict__ w1t)
{
    __shared__ float tile[2][32][33];
    int b = blockIdx.x;                    // [0, 2432)
    int tid = threadIdx.x;
    int d0 = (b % 19) * 64;
    int h0 = ((b / 19) % 16) * 64;
    int e = b / (19 * 16);
    const float* src = W1 + (long)e * D_IN * H_DIM;

    int hs = tid & 15;
    int dr = tid >> 4;
#pragma unroll
    for (int s = 0; s < 4; ++s) {
        int dl = dr + 16 * s;    // 0..63
        int d = d0 + dl;
        float4 v = (d < D_IN)
            ? ((const float4*)(src + (long)d * H_DIM + h0))[hs]
            : (float4){0.f, 0.f, 0.f, 0.f};
        int drl = dl & 31;
        int hl = hs * 4;
        int Th = hl >> 5;
        int hh = hl & 31;
        tile[Th][drl][hh + 0] = v.x;
        tile[Th][drl][hh + 1] = v.y;
        tile[Th][drl][hh + 2] = v.z;
        tile[Th][drl][hh + 3] = v.w;
        if (s == 1) {            // drain d-half 0
            __syncthreads();
            int T2 = tid >> 7, rr = tid & 127;
            int hl2 = rr >> 2, dseg = rr & 3;
            float f[8];
#pragma unroll
            for (int j = 0; j < 8; ++j) f[j] = tile[T2][dseg * 8 + j][hl2];
            union { short8 v8; __hip_bfloat16 hh8[8]; } u;
#pragma unroll
            for (int j = 0; j < 8; ++j) u.hh8[j] = __float2bfloat16(f[j]);
            int h = h0 + T2 * 32 + hl2;
            ((short8*)(w1t + (long)e * H_DIM * D_PAD + (long)h * D_PAD + d0))[dseg] = u.v8;
            __syncthreads();
        }
    }
    __syncthreads();
    {   // drain d-half 1
        int T2 = tid >> 7, rr = tid & 127;
        int hl2 = rr >> 2, dseg = rr & 3;
        float f[8];
#pragma unroll
        for (int j = 0; j < 8; ++j) f[j] = tile[T2][dseg * 8 + j][hl2];
        union { short8 v8; __hip_bfloat16 hh8[8]; } u;
#pragma unroll
        for (int j = 0; j < 8; ++j) u.hh8[j] = __float2bfloat16(f[j]);
        int h = h0 + T2 * 32 + hl2;
        ((short8*)(w1t + (long)e * H_DIM * D_PAD + (long)h * D_PAD + d0 + 32))[dseg] = u.v8;
    }
}

// ---------------- 2. expert GEMM: 256x256 tile, BK=32, 8 waves, 4-deep ring,
//                  counted vmcnt (T3+T4) + setprio (T5) + seg-XOR swizzle (T2) ----------------
// XCD k == expert k (dispatch round-robin): per-expert B (2.4 MB) stays L2-resident.
// LDS ring: 4 slots x (A 16KB + B 16KB) = 128 KiB; stage runs 3 K-tiles ahead of
// compute; the only main-loop wait is a counted s_waitcnt vmcnt(8) once per K-tile
// (= 2 tiles / 8 loads stay in flight across barriers). Raw s_barrier (no implicit
// vmcnt(0) drain, unlike __syncthreads).
__global__ __launch_bounds__(512) void gemm_kernel(
    const __hip_bfloat16* __restrict__ xbf, const __hip_bfloat16* __restrict__ w1t,
    const float* __restrict__ b1, const int* __restrict__ cnt,
    const int* __restrict__ pairRowC,
    __hip_bfloat16* __restrict__ hbuf)
{
    __shared__ __attribute__((aligned(128))) char lds[4 * LDS_BUF];   // 128 KiB

    int bi = blockIdx.x;
    int e = bi & 7;                    // XCD == expert
    int j = bi >> 3;                   // [0, 72)
    int ct = j & 3;                    // 4 col-tiles of 256
    int rt = j >> 2;                   // 18 row-tiles of 256
    int cnt_e = cnt[e * CNT_STRIDE];
    if (rt * 256 >= cnt_e) return;     // fully-padded tile
    int row0 = e * R_CAP + rt * 256;
    int col0 = ct * 256;

    int t = threadIdx.x;
    int lane = t & 63, w = t >> 6;
    int wm = (w >> 2) << 7;            // 0 / 128
    int wn = (w & 3) << 6;             // 0 / 64 / 128 / 192
    int l15 = lane & 15, quad = lane >> 4;
    int qsw = quad ^ ((l15 >> 1) & 3);

    // staging: thread t stages rows (t>>2) and 128+(t>>2), 16B seg (t&3), XOR-swizzled src
    int r1 = t >> 2, seg = t & 3;
    int sw = seg ^ ((r1 >> 1) & 3);    // same for row and row+128 (bits 1-2 equal)
    int ridx1 = pairRowC[row0 + r1];
    int ridx2 = pairRowC[row0 + 128 + r1];
    // pad slots hold poison -> clamp to the zero row of xbf
    ridx1 = ((unsigned)ridx1 > B_ROWS) ? B_ROWS : ridx1;
    ridx2 = ((unsigned)ridx2 > B_ROWS) ? B_ROWS : ridx2;
    const __hip_bfloat16* Arow1 = xbf + (long)ridx1 * D_PAD + sw * 8;
    const __hip_bfloat16* Arow2 = xbf + (long)ridx2 * D_PAD + sw * 8;
    const __hip_bfloat16* Bb = w1t + (long)e * H_DIM * D_PAD + (long)col0 * D_PAD;
    const __hip_bfloat16* Brow1 = Bb + (long)r1 * D_PAD + sw * 8;
    const __hip_bfloat16* Brow2 = Bb + (long)(r1 + 128) * D_PAD + sw * 8;

#define STAGE_A(wbuf, koff) do { \
    load_lds16(Arow1 + (koff), lds + (wbuf) * LDS_BUF + t * 16); \
    load_lds16(Arow2 + (koff), lds + (wbuf) * LDS_BUF + 8192 + t * 16); } while (0)
#define STAGE_B(wbuf, koff) do { \
    load_lds16(Brow1 + (koff), lds + (wbuf) * LDS_BUF + 16384 + t * 16); \
    load_lds16(Brow2 + (koff), lds + (wbuf) * LDS_BUF + 24576 + t * 16); } while (0)

    f32x4 acc[8][4];
#pragma unroll
    for (int i = 0; i < 8; ++i)
#pragma unroll
        for (int j2 = 0; j2 < 4; ++j2) acc[i][j2] = (f32x4){0.f, 0.f, 0.f, 0.f};

    // prologue: stage tiles 0,1,2 (12 loads/thread); drain tile 0 only (counted)
    STAGE_A(0, 0);  STAGE_B(0, 0);
    STAGE_A(1, 32); STAGE_B(1, 32);
    STAGE_A(2, 64); STAGE_B(2, 64);
    asm volatile("s_waitcnt vmcnt(8)" ::: "memory");
    __builtin_amdgcn_s_barrier();

    int rb = 0;
#pragma unroll 1
    for (int kt = 0; kt < NT; ++kt) {
        char* ldsA = lds + rb * LDS_BUF;
        char* ldsB = ldsA + 16384;
        int wb = rb + 3; if (wb >= 4) wb -= 4;   // ring slot of tile kt+3 (== kt-1's, already consumed)
        bool doStage = (kt + 3 < NT);
        int koff = (kt + 3) * 32;

        bf16x8 af[8], bfr[4];
        // ---------- phase A: read A frags + B n0-1, stage A of kt+3, MFMA n0-1 ----------
#pragma unroll
        for (int i = 0; i < 8; ++i)
            af[i] = *(const bf16x8*)(ldsA + (wm + i * 16 + l15) * 64 + qsw * 16);
#pragma unroll
        for (int j2 = 0; j2 < 2; ++j2)
            bfr[j2] = *(const bf16x8*)(ldsB + (wn + j2 * 16 + l15) * 64 + qsw * 16);
        if (doStage) STAGE_A(wb, koff);
        __builtin_amdgcn_s_barrier();
        asm volatile("s_waitcnt lgkmcnt(0)" ::: "memory");
        __builtin_amdgcn_sched_barrier(0);
        __builtin_amdgcn_s_setprio(1);
#pragma unroll
        for (int i = 0; i < 8; ++i)
#pragma unroll
            for (int j2 = 0; j2 < 2; ++j2)
                acc[i][j2] = __builtin_amdgcn_mfma_f32_16x16x32_bf16(af[i], bfr[j2], acc[i][j2], 0, 0, 0);
        __builtin_amdgcn_s_setprio(0);
        __builtin_amdgcn_s_barrier();

        // ---------- phase B: read B n2-3, stage B of kt+3, MFMA n2-3, counted vmcnt ----------
#pragma unroll
        for (int j2 = 2; j2 < 4; ++j2)
            bfr[j2] = *(const bf16x8*)(ldsB + (wn + j2 * 16 + l15) * 64 + qsw * 16);
        if (doStage) STAGE_B(wb, koff);
        __builtin_amdgcn_s_barrier();
        asm volatile("s_waitcnt lgkmcnt(0)" ::: "memory");
        __builtin_amdgcn_sched_barrier(0);
        __builtin_amdgcn_s_setprio(1);
#pragma unroll
        for (int i = 0; i < 8; ++i)
#pragma unroll
            for (int j2 = 2; j2 < 4; ++j2)
                acc[i][j2] = __builtin_amdgcn_mfma_f32_16x16x32_bf16(af[i], bfr[j2], acc[i][j2], 0, 0, 0);
        __builtin_amdgcn_s_setprio(0);
        // drain exactly tile kt+1's 4 loads; keep kt+2, kt+3 in flight
        if (kt < NT - 3)       asm volatile("s_waitcnt vmcnt(8)" ::: "memory");
        else if (kt == NT - 3) asm volatile("s_waitcnt vmcnt(4)" ::: "memory");
        else                   asm volatile("s_waitcnt vmcnt(0)" ::: "memory");
        __builtin_amdgcn_s_barrier();

        rb += 1; if (rb >= 4) rb -= 4;
    }
#undef STAGE_A
#undef STAGE_B

    // epilogue: bias + bf16 store (C/D layout: col = lane&15, row = quad*4 + r)
#pragma unroll
    for (int i = 0; i < 8; ++i) {
        int lr = wm + i * 16 + quad * 4;
#pragma unroll
        for (int j2 = 0; j2 < 4; ++j2) {
            int gc = col0 + wn + j2 * 16 + l15;
            float bias = b1[e * H_DIM + gc];
#pragma unroll
            for (int r = 0; r < 4; ++r) {
                float v = acc[i][j2][r] + bias;
                hbuf[(long)(row0 + lr + r) * H_DIM + gc] = __float2bfloat16(v);
            }
        }
    }
}

// ---------------- 3. LN + ReLU + head + sigmoid + combine (wave-per-row) ----------------
__global__ __launch_bounds__(256) void ln_head_kernel(
    const __hip_bfloat16* __restrict__ hbuf, const int* __restrict__ cnt,
    const int* __restrict__ pairRowC, const float* __restrict__ pairGateC,
    const float* __restrict__ g1, const float* __restrict__ be1,
    const float* __restrict__ W2, const float* __restrict__ b2,
    float* __restrict__ y)
{
    int tid = threadIdx.x;
    int p = blockIdx.x * 4 + (tid >> 6);
    int e = p / R_CAP;
    int slot = p - e * R_CAP;
    if (slot >= cnt[e * CNT_STRIDE]) return;   // padding slot (incl. poisoned)

    int lane = tid & 63;
    int row = pairRowC[p];
    float gate = pairGateC[p];
    const short4v* hr = (const short4v*)(hbuf + (long)p * H_DIM);

    float v[16];
    float sum = 0.f, sumsq = 0.f;
#pragma unroll
    for (int k = 0; k < 4; ++k) {
        union { short4v s; __hip_bfloat16 h[4]; } hv;
        hv.s = hr[lane + k * 64];
#pragma unroll
        for (int j = 0; j < 4; ++j) {
            float f = __bfloat162float(hv.h[j]);
            v[k * 4 + j] = f;
            sum += f;
            sumsq += f * f;
        }
    }
#pragma unroll
    for (int off = 32; off > 0; off >>= 1) {
        sum += __shfl_xor(sum, off, 64);
        sumsq += __shfl_xor(sumsq, off, 64);
    }
    float mu = sum * (1.f / H_DIM);
    float var = sumsq * (1.f / H_DIM) - mu * mu;
    float rstd = rsqrtf(var + LN_EPS);

    float z = 0.f;
#pragma unroll
    for (int k = 0; k < 4; ++k) {
        float4 gv = ((const float4*)(g1 + e * H_DIM))[lane + k * 64];
        float4 bv = ((const float4*)(be1 + e * H_DIM))[lane + k * 64];
        float4 wv = ((const float4*)(W2 + e * H_DIM))[lane + k * 64];
        z += fmaxf((v[k*4+0] - mu) * rstd * gv.x + bv.x, 0.f) * wv.x;
        z += fmaxf((v[k*4+1] - mu) * rstd * gv.y + bv.y, 0.f) * wv.y;
        z += fmaxf((v[k*4+2] - mu) * rstd * gv.z + bv.z, 0.f) * wv.z;
        z += fmaxf((v[k*4+3] - mu) * rstd * gv.w + bv.w, 0.f) * wv.w;
    }
#pragma unroll
    for (int off = 32; off > 0; off >>= 1) z += __shfl_xor(z, off, 64);
    if (lane == 0) {
        float zt = z + b2[e];
        float o = 1.f / (1.f + expf(-zt));
        atomicAdd(&y[row], gate * o);
    }
}

extern "C" void kernel_launch(void* const* d_in, const int* in_sizes, int n_in,
                              void* d_out, int out_size, void* d_ws, size_t ws_size,
                              hipStream_t stream)
{
    const float* x   = (const float*)d_in[0];
    const float* wg  = (const float*)d_in[1];
    const float* W1  = (const float*)d_in[2];
    const float* b1  = (const float*)d_in[3];
    const float* g1  = (const float*)d_in[4];
    const float* be1 = (const float*)d_in[5];
    const float* W2  = (const float*)d_in[6];
    const float* b2  = (const float*)d_in[7];
    float* y = (float*)d_out;

    char* ws = (char*)d_ws;
    int*   cnt       = (int*)(ws + O_CNT);
    int*   pairRowC  = (int*)(ws + O_PROWC);
    float* pairGateC = (float*)(ws + O_PGATEC);
    __hip_bfloat16* xbf  = (__hip_bfloat16*)(ws + O_XBF);
    __hip_bfloat16* w1t  = (__hip_bfloat16*)(ws + O_W1T);
    __hip_bfloat16* hbuf = (__hip_bfloat16*)(ws + O_HBUF);

    hipMemsetAsync(cnt, 0, 512, stream);

    gating_kernel<<<GATING_BLOCKS + 1, 256, 0, stream>>>(x, wg, cnt, pairRowC,
                                                         pairGateC, xbf, y);
    w1t_kernel<<<W1T_BLOCKS, 256, 0, stream>>>(W1, w1t);
    gemm_kernel<<<GEMM_BLOCKS, 512, 0, stream>>>(xbf, w1t, b1, cnt, pairRowC, hbuf);
    ln_head_kernel<<<CAP / 4, 256, 0, stream>>>(hbuf, cnt, pairRowC, pairGateC,
                                                g1, be1, W2, b2, y);
}

// Round 2
// 307.351 us; speedup vs baseline: 1.0603x; 1.0603x over previous
//
#include <hip/hip_runtime.h>
#include <hip/hip_bf16.h>
#include <stdint.h>

#define B_ROWS 16384
#define D_IN   1200
#define D_PAD  1216      // 19 * 64
#define N_EXP  8
#define H_DIM  1024
#define R_CAP  4608      // fixed per-expert region (counts ~4096 +- 55; 9 sigma margin)
#define CAP    36864     // 8 * R_CAP
#define N_RT   288       // CAP / 128 row-tiles (36 per expert/XCD)
#define LN_EPS 1e-5f
#define GATE_EPS 1e-6f
#define CNT_STRIDE 16    // pad expert counters to separate 64B cache lines

// ---- workspace layout (bytes) ----
#define O_CNT    0           // 512 B
#define O_PROWC  512         // 36864 ints  -> 147968
#define O_PGATEC 147968      // 36864 floats -> 295424
#define O_XBF    295424      // 16385*1216*2 -> 40143744 (row 16384 = zeros)
#define O_W1T    40143744    // 8*1024*1216*2 -> 60066688
#define O_HBUF   60066688    // 36864*1024*2 -> 135564160 (~130 MB total)

#define GATING_BLOCKS (B_ROWS / 16)       // 1024 (4 rows/wave, 4 waves)
#define W1T_BLOCKS    (19 * 16 * 8)       // 2432  (64d x 64h tiles)
#define PREP_BLOCKS   (GATING_BLOCKS + 1 + W1T_BLOCKS)   // 3457

#define NT        (D_PAD / 32)            // 38 K-tiles
#define SLOT_SZ   16384                   // A 8KB + B 8KB per ring slot

typedef short bf16x8 __attribute__((ext_vector_type(8)));
typedef short short8 __attribute__((ext_vector_type(8)));
typedef short short4v __attribute__((ext_vector_type(4)));
typedef float f32x4 __attribute__((ext_vector_type(4)));

__device__ __forceinline__ void load_lds16(const void* gptr, void* ldsptr) {
    __builtin_amdgcn_global_load_lds(
        (__attribute__((address_space(1))) void*)const_cast<void*>(gptr),
        (__attribute__((address_space(3))) void*)ldsptr, 16, 0, 0);
}

__device__ __forceinline__ short4v pack_bf16x4(float4 a) {
    union { short4v v; __hip_bfloat16 h[4]; } u;
    u.h[0] = __float2bfloat16(a.x); u.h[1] = __float2bfloat16(a.y);
    u.h[2] = __float2bfloat16(a.z); u.h[3] = __float2bfloat16(a.w);
    return u.v;
}

// ---------------- 1. prep: gating (blocks 0..1024) + W1 transpose (blocks 1025..) ----------------
// gating and w1t are independent; merging lets the BW-light transpose overlap the
// BW-heavy gating instead of serializing, and saves a launch gap.
__global__ __launch_bounds__(256) void prep_kernel(
    const float* __restrict__ x, const float* __restrict__ wg,
    int* __restrict__ cnt, int* __restrict__ pairRowC, float* __restrict__ pairGateC,
    __hip_bfloat16* __restrict__ xbf, float* __restrict__ y,
    const float* __restrict__ W1, __hip_bfloat16* __restrict__ w1t)
{
    __shared__ int lcnt[N_EXP];
    __shared__ int base[N_EXP];
    __shared__ float tile[2][32][33];
    int bx = blockIdx.x;
    int tid = threadIdx.x;

    if (bx > GATING_BLOCKS) {
        // ---- w1t part: W1 [E][D][H] fp32 -> w1t [E][H][D_PAD] bf16 ----
        int b = bx - GATING_BLOCKS - 1;        // [0, 2432)
        int d0 = (b % 19) * 64;
        int h0 = ((b / 19) % 16) * 64;
        int e = b / (19 * 16);
        const float* src = W1 + (long)e * D_IN * H_DIM;

        int hs = tid & 15;
        int dr = tid >> 4;
#pragma unroll
        for (int s = 0; s < 4; ++s) {
            int dl = dr + 16 * s;    // 0..63
            int d = d0 + dl;
            float4 v = (d < D_IN)
                ? ((const float4*)(src + (long)d * H_DIM + h0))[hs]
                : (float4){0.f, 0.f, 0.f, 0.f};
            int drl = dl & 31;
            int hl = hs * 4;
            int Th = hl >> 5;
            int hh = hl & 31;
            tile[Th][drl][hh + 0] = v.x;
            tile[Th][drl][hh + 1] = v.y;
            tile[Th][drl][hh + 2] = v.z;
            tile[Th][drl][hh + 3] = v.w;
            if (s == 1) {            // drain d-half 0
                __syncthreads();
                int T2 = tid >> 7, rr = tid & 127;
                int hl2 = rr >> 2, dseg = rr & 3;
                float f[8];
#pragma unroll
                for (int jj = 0; jj < 8; ++jj) f[jj] = tile[T2][dseg * 8 + jj][hl2];
                union { short8 v8; __hip_bfloat16 hh8[8]; } u;
#pragma unroll
                for (int jj = 0; jj < 8; ++jj) u.hh8[jj] = __float2bfloat16(f[jj]);
                int h = h0 + T2 * 32 + hl2;
                ((short8*)(w1t + (long)e * H_DIM * D_PAD + (long)h * D_PAD + d0))[dseg] = u.v8;
                __syncthreads();
            }
        }
        __syncthreads();
        {   // drain d-half 1
            int T2 = tid >> 7, rr = tid & 127;
            int hl2 = rr >> 2, dseg = rr & 3;
            float f[8];
#pragma unroll
            for (int jj = 0; jj < 8; ++jj) f[jj] = tile[T2][dseg * 8 + jj][hl2];
            union { short8 v8; __hip_bfloat16 hh8[8]; } u;
#pragma unroll
            for (int jj = 0; jj < 8; ++jj) u.hh8[jj] = __float2bfloat16(f[jj]);
            int h = h0 + T2 * 32 + hl2;
            ((short8*)(w1t + (long)e * H_DIM * D_PAD + (long)h * D_PAD + d0 + 32))[dseg] = u.v8;
        }
        return;
    }

    if (bx == GATING_BLOCKS) {   // zero the padding row of xbf
        short8* xrow = (short8*)(xbf + (long)B_ROWS * D_PAD);
        if (tid < 152) xrow[tid] = (short8){0, 0, 0, 0, 0, 0, 0, 0};
        return;
    }

    // ---- gating part ----
    if (tid < N_EXP) lcnt[tid] = 0;
    if (tid < 16) y[bx * 16 + tid] = 0.f;
    __syncthreads();

    int widx = tid >> 6;
    int lane = tid & 63;
    int rowbase = bx * 16 + widx * 4;
    const float* xw = x + (long)rowbase * D_IN;

    float acc[4][8];
#pragma unroll
    for (int r = 0; r < 4; ++r)
#pragma unroll
        for (int e = 0; e < N_EXP; ++e) acc[r][e] = 0.f;

    for (int i = lane; i < 304; i += 64) {
        if (i < 300) {
            const float4* wv4 = (const float4*)(wg + (long)i * 32);
            float4 w0 = wv4[0], w1v = wv4[1], w2 = wv4[2], w3 = wv4[3],
                   w4 = wv4[4], w5 = wv4[5], w6 = wv4[6], w7 = wv4[7];
#pragma unroll
            for (int r = 0; r < 4; ++r) {
                float4 xv = ((const float4*)(xw + (long)r * D_IN))[i];
                acc[r][0] += xv.x * w0.x + xv.y * w2.x + xv.z * w4.x + xv.w * w6.x;
                acc[r][1] += xv.x * w0.y + xv.y * w2.y + xv.z * w4.y + xv.w * w6.y;
                acc[r][2] += xv.x * w0.z + xv.y * w2.z + xv.z * w4.z + xv.w * w6.z;
                acc[r][3] += xv.x * w0.w + xv.y * w2.w + xv.z * w4.w + xv.w * w6.w;
                acc[r][4] += xv.x * w1v.x + xv.y * w3.x + xv.z * w5.x + xv.w * w7.x;
                acc[r][5] += xv.x * w1v.y + xv.y * w3.y + xv.z * w5.y + xv.w * w7.y;
                acc[r][6] += xv.x * w1v.z + xv.y * w3.z + xv.z * w5.z + xv.w * w7.z;
                acc[r][7] += xv.x * w1v.w + xv.y * w3.w + xv.z * w5.w + xv.w * w7.w;
                ((short4v*)(xbf + (long)(rowbase + r) * D_PAD))[i] = pack_bf16x4(xv);
            }
        } else {
#pragma unroll
            for (int r = 0; r < 4; ++r)
                ((short4v*)(xbf + (long)(rowbase + r) * D_PAD))[i] = (short4v){0, 0, 0, 0};
        }
    }

#pragma unroll
    for (int r = 0; r < 4; ++r)
#pragma unroll
        for (int e = 0; e < N_EXP; ++e) {
            float v = acc[r][e];
#pragma unroll
            for (int off = 32; off > 0; off >>= 1) v += __shfl_xor(v, off, 64);
            acc[r][e] = v;
        }

    float my[N_EXP];
#pragma unroll
    for (int e = 0; e < N_EXP; ++e) my[e] = acc[0][e];
#pragma unroll
    for (int r = 1; r < 4; ++r)
#pragma unroll
        for (int e = 0; e < N_EXP; ++e)
            if (lane == r) my[e] = acc[r][e];

    int i0 = 0, i1 = 1, s0 = 0, s1 = 0;
    float g0 = 0.f, g1 = 0.f;
    if (lane < 4) {
        float m = my[0];
#pragma unroll
        for (int e = 1; e < N_EXP; ++e) m = fmaxf(m, my[e]);
        float p[N_EXP], s = 0.f;
#pragma unroll
        for (int e = 0; e < N_EXP; ++e) { p[e] = expf(my[e] - m); s += p[e]; }
#pragma unroll
        for (int e = 1; e < N_EXP; ++e) if (p[e] > p[i0]) i0 = e;
        i1 = (i0 == 0) ? 1 : 0;
#pragma unroll
        for (int e = 0; e < N_EXP; ++e) if (e != i0 && p[e] > p[i1]) i1 = e;
        float v0 = p[i0] / s, v1 = p[i1] / s;
        float inv = 1.f / (v0 + v1 + GATE_EPS);
        g0 = v0 * inv; g1 = v1 * inv;
        s0 = atomicAdd(&lcnt[i0], 1);
        s1 = atomicAdd(&lcnt[i1], 1);
    }
    __syncthreads();
    if (tid < N_EXP) base[tid] = atomicAdd(&cnt[tid * CNT_STRIDE], lcnt[tid]);
    __syncthreads();
    if (lane < 4) {
        int row = rowbase + lane;
        int p0 = i0 * R_CAP + base[i0] + s0;
        pairRowC[p0] = row; pairGateC[p0] = g0;
        int p1 = i1 * R_CAP + base[i1] + s1;
        pairRowC[p1] = row; pairGateC[p1] = g1;
    }
}

// ---------------- 2. expert GEMM (128x128, BK=32, XCD==expert, indirect clamped A)
//      3-slot LDS ring + counted vmcnt + single raw s_barrier per K-tile.
//      Fragment-read/MFMA interleave is left entirely to the compiler (m97-style
//      fine-grained lgkmcnt); only the staging pipeline is hand-managed, so the
//      global_load_lds queue is never drained to 0 in steady state. ----------------
__global__ __launch_bounds__(256) void gemm_kernel(
    const __hip_bfloat16* __restrict__ xbf, const __hip_bfloat16* __restrict__ w1t,
    const float* __restrict__ b1, const int* __restrict__ cnt,
    const int* __restrict__ pairRowC,
    __hip_bfloat16* __restrict__ hbuf)
{
    // bi&7 = XCD (dispatch round-robin) = expert: XCD k owns row-tiles
    // [36k, 36k+36) == expert k's region; its 2.4 MB B stays L2-resident.
    int bi = blockIdx.x;
    int xcd = bi & 7;
    int j = bi >> 3;                 // [0, 288)
    int col0 = (j & 7) << 7;
    int rt = xcd * 36 + (j >> 3);    // [0, 288)
    int row0 = rt << 7;
    int e = xcd;                     // rt/36 == xcd by construction
    int cnt_e = cnt[e * CNT_STRIDE];
    if (row0 - e * R_CAP >= cnt_e) return;   // fully-padded tile

    __shared__ __attribute__((aligned(128))) char lds[3 * SLOT_SZ];   // 48 KiB ring

    int t = threadIdx.x;
    int lane = t & 63, w = t >> 6;
    int wm = (w >> 1) * 64, wn = (w & 1) * 64;
    int l15 = lane & 15, quad = lane >> 4;
    int qsw = quad ^ ((l15 >> 1) & 3);

    f32x4 acc[4][4];
#pragma unroll
    for (int i = 0; i < 4; ++i)
#pragma unroll
        for (int j2 = 0; j2 < 4; ++j2) acc[i][j2] = (f32x4){0.f, 0.f, 0.f, 0.f};

    int r1 = t >> 2, seg = t & 3;
    int sw = seg ^ ((r1 >> 1) & 3);
    int ridx1 = pairRowC[row0 + r1];
    int ridx2 = pairRowC[row0 + 64 + r1];
    // pad slots hold poison -> clamp to the zero row of xbf
    ridx1 = ((unsigned)ridx1 > B_ROWS) ? B_ROWS : ridx1;
    ridx2 = ((unsigned)ridx2 > B_ROWS) ? B_ROWS : ridx2;
    const __hip_bfloat16* Arow1 = xbf + (long)ridx1 * D_PAD + sw * 8;
    const __hip_bfloat16* Arow2 = xbf + (long)ridx2 * D_PAD + sw * 8;
    const __hip_bfloat16* Bb = w1t + (long)e * H_DIM * D_PAD + (long)col0 * D_PAD;
    const __hip_bfloat16* Brow1 = Bb + (long)r1 * D_PAD + sw * 8;
    const __hip_bfloat16* Brow2 = Bb + (long)(r1 + 64) * D_PAD + sw * 8;

#define STAGE(sl, koff) do { \
    char* sb_ = lds + (sl) * SLOT_SZ; \
    load_lds16(Arow1 + (koff), sb_ + t * 16); \
    load_lds16(Arow2 + (koff), sb_ + 4096 + t * 16); \
    load_lds16(Brow1 + (koff), sb_ + 8192 + t * 16); \
    load_lds16(Brow2 + (koff), sb_ + 12288 + t * 16); } while (0)

    // prologue: stage tiles 0 and 1; wait tile 0 only (tile 1's 4 loads stay in flight)
    STAGE(0, 0);
    STAGE(1, 32);
    asm volatile("s_waitcnt vmcnt(4)" ::: "memory");
    __builtin_amdgcn_s_barrier();
    asm volatile("" ::: "memory");

    int cur = 0;
    for (int kt = 0; kt < NT; ++kt) {
        int nxt2 = cur + 2; if (nxt2 >= 3) nxt2 -= 3;
        if (kt + 2 < NT) STAGE(nxt2, (kt + 2) * 32);   // slot was last read at iter kt-1

        const char* lAc = lds + cur * SLOT_SZ;
        const char* lBc = lAc + 8192;
        bf16x8 af[4], bfr[4];
#pragma unroll
        for (int i = 0; i < 4; ++i)
            af[i] = *(const bf16x8*)(lAc + (wm + i * 16 + l15) * 64 + qsw * 16);
#pragma unroll
        for (int j2 = 0; j2 < 4; ++j2)
            bfr[j2] = *(const bf16x8*)(lBc + (wn + j2 * 16 + l15) * 64 + qsw * 16);
#pragma unroll
        for (int i = 0; i < 4; ++i)
#pragma unroll
            for (int j2 = 0; j2 < 4; ++j2)
                acc[i][j2] = __builtin_amdgcn_mfma_f32_16x16x32_bf16(af[i], bfr[j2], acc[i][j2], 0, 0, 0);

        // end of tile: tile kt+1's loads must have landed; keep kt+2's in flight
        if (kt + 2 < NT)      asm volatile("s_waitcnt vmcnt(4)" ::: "memory");
        else if (kt + 1 < NT) asm volatile("s_waitcnt vmcnt(0)" ::: "memory");
        if (kt + 1 < NT) {
            __builtin_amdgcn_s_barrier();
            asm volatile("" ::: "memory");
        }
        cur += 1; if (cur >= 3) cur -= 3;
    }
#undef STAGE

    // epilogue: bias + bf16 store (C/D layout: col = lane&15, row = quad*4 + r)
#pragma unroll
    for (int i = 0; i < 4; ++i) {
        int lr = wm + i * 16 + quad * 4;
#pragma unroll
        for (int j2 = 0; j2 < 4; ++j2) {
            int gc = col0 + wn + j2 * 16 + l15;
            float bias = b1[e * H_DIM + gc];
#pragma unroll
            for (int r = 0; r < 4; ++r) {
                float v = acc[i][j2][r] + bias;
                hbuf[(long)(row0 + lr + r) * H_DIM + gc] = __float2bfloat16(v);
            }
        }
    }
}

// ---------------- 3. LN + ReLU + head + sigmoid + combine (wave-per-row) ----------------
__global__ __launch_bounds__(256) void ln_head_kernel(
    const __hip_bfloat16* __restrict__ hbuf, const int* __restrict__ cnt,
    const int* __restrict__ pairRowC, const float* __restrict__ pairGateC,
    const float* __restrict__ g1, const float* __restrict__ be1,
    const float* __restrict__ W2, const float* __restrict__ b2,
    float* __restrict__ y)
{
    int tid = threadIdx.x;
    int p = blockIdx.x * 4 + (tid >> 6);
    int e = p / R_CAP;
    int slot = p - e * R_CAP;
    if (slot >= cnt[e * CNT_STRIDE]) return;   // padding slot (incl. poisoned)

    int lane = tid & 63;
    int row = pairRowC[p];
    float gate = pairGateC[p];
    const short4v* hr = (const short4v*)(hbuf + (long)p * H_DIM);

    float v[16];
    float sum = 0.f, sumsq = 0.f;
#pragma unroll
    for (int k = 0; k < 4; ++k) {
        union { short4v s; __hip_bfloat16 h[4]; } hv;
        hv.s = hr[lane + k * 64];
#pragma unroll
        for (int j = 0; j < 4; ++j) {
            float f = __bfloat162float(hv.h[j]);
            v[k * 4 + j] = f;
            sum += f;
            sumsq += f * f;
        }
    }
#pragma unroll
    for (int off = 32; off > 0; off >>= 1) {
        sum += __shfl_xor(sum, off, 64);
        sumsq += __shfl_xor(sumsq, off, 64);
    }
    float mu = sum * (1.f / H_DIM);
    float var = sumsq * (1.f / H_DIM) - mu * mu;
    float rstd = rsqrtf(var + LN_EPS);

    float z = 0.f;
#pragma unroll
    for (int k = 0; k < 4; ++k) {
        float4 gv = ((const float4*)(g1 + e * H_DIM))[lane + k * 64];
        float4 bv = ((const float4*)(be1 + e * H_DIM))[lane + k * 64];
        float4 wv = ((const float4*)(W2 + e * H_DIM))[lane + k * 64];
        z += fmaxf((v[k*4+0] - mu) * rstd * gv.x + bv.x, 0.f) * wv.x;
        z += fmaxf((v[k*4+1] - mu) * rstd * gv.y + bv.y, 0.f) * wv.y;
        z += fmaxf((v[k*4+2] - mu) * rstd * gv.z + bv.z, 0.f) * wv.z;
        z += fmaxf((v[k*4+3] - mu) * rstd * gv.w + bv.w, 0.f) * wv.w;
    }
#pragma unroll
    for (int off = 32; off > 0; off >>= 1) z += __shfl_xor(z, off, 64);
    if (lane == 0) {
        float zt = z + b2[e];
        float o = 1.f / (1.f + expf(-zt));
        atomicAdd(&y[row], gate * o);
    }
}

extern "C" void kernel_launch(void* const* d_in, const int* in_sizes, int n_in,
                              void* d_out, int out_size, void* d_ws, size_t ws_size,
                              hipStream_t stream)
{
    const float* x   = (const float*)d_in[0];
    const float* wg  = (const float*)d_in[1];
    const float* W1  = (const float*)d_in[2];
    const float* b1  = (const float*)d_in[3];
    const float* g1  = (const float*)d_in[4];
    const float* be1 = (const float*)d_in[5];
    const float* W2  = (const float*)d_in[6];
    const float* b2  = (const float*)d_in[7];
    float* y = (float*)d_out;

    char* ws = (char*)d_ws;
    int*   cnt       = (int*)(ws + O_CNT);
    int*   pairRowC  = (int*)(ws + O_PROWC);
    float* pairGateC = (float*)(ws + O_PGATEC);
    __hip_bfloat16* xbf  = (__hip_bfloat16*)(ws + O_XBF);
    __hip_bfloat16* w1t  = (__hip_bfloat16*)(ws + O_W1T);
    __hip_bfloat16* hbuf = (__hip_bfloat16*)(ws + O_HBUF);

    hipMemsetAsync(cnt, 0, 512, stream);

    prep_kernel<<<PREP_BLOCKS, 256, 0, stream>>>(x, wg, cnt, pairRowC, pairGateC,
                                                 xbf, y, W1, w1t);
    gemm_kernel<<<N_RT * 8, 256, 0, stream>>>(xbf, w1t, b1, cnt, pairRowC, hbuf);
    ln_head_kernel<<<CAP / 4, 256, 0, stream>>>(hbuf, cnt, pairRowC, pairGateC,
                                                g1, be1, W2, b2, y);
}